// Round 11
// baseline (296.131 us; speedup 1.0000x reference)
//
#include <hip/hip_runtime.h>
#include <math.h>

// ADIOS contrastive loss, MI355X — fp16 MFMA (K=512), 128^2 tile, 4 waves,
// triple-buffered counted-vmcnt pipeline + T2 XOR LDS swizzle.
// R8 measured: 131 us gemm, MfmaUtil 29, SQ_LDS_BANK_CONFLICT 1.05e7 (8-way
// read conflict: 16 lanes x stride-64B rows -> 2 banks). Swizzle k-slot by
// ((row>>1)&3): banks = 16(row&1)+4*k' -> 8 banks, 2-way = free (m136).
// Swizzle applied on GLOBAL source (gload_lds dest stays linear) and on reads.

#define B_ROWS 4096
#define M_MASK 4
#define D_DIM  512
#define N_COLS ((M_MASK + 1) * B_ROWS)   // 20480
#define GK     D_DIM                     // 512 fp16
#define NT     (GK / 32)                 // 16 K-tiles

typedef _Float16 f16x8 __attribute__((ext_vector_type(8)));
typedef float    f32x4 __attribute__((ext_vector_type(4)));

__device__ __forceinline__ float inv_temp(const int* __restrict__ itp) {
    int it = *itp;
    double T;
    if (it >= 300000) {
        T = 0.05;
    } else {
        double p = (double)it / 300000.0;
        T = 0.05 + 0.5 * (0.2 - 0.05) * (1.0 + cos(3.14159265358979323846 * p));
    }
    return (float)(1.0 / T);
}

// One wave per row: L2-normalize, cast fp16, store [N_COLS][GK].
// Extra block zeroes denom/pos (8192 floats) + ticket.
__global__ __launch_bounds__(256) void prep_kernel(
        const float* __restrict__ orig, const float* __restrict__ masked,
        _Float16* __restrict__ E, float* __restrict__ zbuf, int* __restrict__ ticket) {
    if (blockIdx.x == N_COLS / 4) {
        float4 z = {0.f, 0.f, 0.f, 0.f};
        #pragma unroll
        for (int i = 0; i < 8; ++i)
            *(float4*)(zbuf + threadIdx.x * 4 + i * 1024) = z;  // 8192 floats
        if (threadIdx.x == 0) *ticket = 0;
        return;
    }
    int gw = blockIdx.x * 4 + (threadIdx.x >> 6);
    int l  = threadIdx.x & 63;
    const float* row = (gw < B_ROWS) ? orig + (size_t)gw * D_DIM
                                     : masked + (size_t)(gw - B_ROWS) * D_DIM;
    float4 a = *(const float4*)(row + l * 8);
    float4 b = *(const float4*)(row + l * 8 + 4);
    float s = a.x*a.x + a.y*a.y + a.z*a.z + a.w*a.w
            + b.x*b.x + b.y*b.y + b.z*b.z + b.w*b.w;
    #pragma unroll
    for (int off = 1; off < 64; off <<= 1) s += __shfl_xor(s, off, 64);
    float inv = 1.0f / fmaxf(sqrtf(s), 1e-12f);

    f16x8 h;
    h[0] = (_Float16)(a.x*inv); h[1] = (_Float16)(a.y*inv);
    h[2] = (_Float16)(a.z*inv); h[3] = (_Float16)(a.w*inv);
    h[4] = (_Float16)(b.x*inv); h[5] = (_Float16)(b.y*inv);
    h[6] = (_Float16)(b.z*inv); h[7] = (_Float16)(b.w*inv);
    *(f16x8*)(E + (size_t)gw * GK + l * 8) = h;
}

// 128x128 tile, 4 waves (2x2). 3 LDS slots of (A[128][32] | B[128][32]), swizzled.
// Last block (ticket) computes the final loss.
__global__ __launch_bounds__(256, 3) void gemm_kernel(
        const _Float16* __restrict__ E, const int* __restrict__ itp,
        float* __restrict__ denom, float* __restrict__ pos,
        int* __restrict__ ticket, float* __restrict__ out) {
    __shared__ _Float16 LDS[3 * 8192];   // 48 KiB

    const int tid = threadIdx.x;
    const int l   = tid & 63;
    const int wid = tid >> 6;
    const int wr  = wid >> 1;
    const int wc  = wid & 1;

    const int rowTile = blockIdx.x & 31;     // 4096/128
    const int colTile = blockIdx.x >> 5;     // 20480/128
    const int rowBase = rowTile * 128;
    const int colBase = colTile * 128;

    const _Float16* Ag = E + (size_t)rowBase * GK;
    const _Float16* Bg = E + (size_t)colBase * GK;

    // T2: LDS (r, slot k) holds global k-slot (k ^ ((r>>1)&3)).
    // Staging: lane l writes row r = rc + (l>>2), slot k = l&3; (r>>1)&3 = (l>>3)&3.
    const int ksrc = (((l & 3) ^ ((l >> 3) & 3)) * 8);
    auto STAGE = [&](int t) {
        _Float16* base = LDS + (t % 3) * 8192;
        const int kb = t * 32;
        #pragma unroll
        for (int i = 0; i < 2; ++i) {
            const int rc = wid * 32 + i * 16;
            const int r  = rc + (l >> 2);
            const size_t go = (size_t)r * GK + kb + ksrc;
            __builtin_amdgcn_global_load_lds(
                (const __attribute__((address_space(1))) void*)(Ag + go),
                (__attribute__((address_space(3))) void*)(base + rc * 32), 16, 0, 0);
            __builtin_amdgcn_global_load_lds(
                (const __attribute__((address_space(1))) void*)(Bg + go),
                (__attribute__((address_space(3))) void*)(base + 4096 + rc * 32), 16, 0, 0);
        }
    };

    // Read: lane wants (row = *+ (l&15), slot l>>4) -> LDS slot (l>>4)^((row>>1)&3),
    // and (row>>1)&3 = (l>>1)&3 since the row base is a multiple of 16.
    const int koff = (((l >> 4) ^ ((l >> 1) & 3)) * 8);
    f16x8 af[4], bf[4];
    auto FRAGS = [&](int t) {
        const _Float16* base = LDS + (t % 3) * 8192;
        #pragma unroll
        for (int m = 0; m < 4; ++m)
            af[m] = *(const f16x8*)(base + (wr * 64 + m * 16 + (l & 15)) * 32 + koff);
        #pragma unroll
        for (int n = 0; n < 4; ++n)
            bf[n] = *(const f16x8*)(base + 4096 + (wc * 64 + n * 16 + (l & 15)) * 32 + koff);
    };

    f32x4 acc[4][4];
    #pragma unroll
    for (int m = 0; m < 4; ++m)
        #pragma unroll
        for (int n = 0; n < 4; ++n)
            #pragma unroll
            for (int j = 0; j < 4; ++j) acc[m][n][j] = 0.f;

    auto MM = [&]() {
        __builtin_amdgcn_s_setprio(1);
        #pragma unroll
        for (int m = 0; m < 4; ++m)
            #pragma unroll
            for (int n = 0; n < 4; ++n)
                acc[m][n] = __builtin_amdgcn_mfma_f32_16x16x32_f16(af[m], bf[n], acc[m][n], 0, 0, 0);
        __builtin_amdgcn_s_setprio(0);
    };

#define BAR()  __builtin_amdgcn_s_barrier()
#define LGKM0() { asm volatile("s_waitcnt lgkmcnt(0)" ::: "memory"); \
                  __builtin_amdgcn_sched_barrier(0); }
#define VM(n)  asm volatile("s_waitcnt vmcnt(" #n ")" ::: "memory")

    STAGE(0); STAGE(1);
    VM(4);
    BAR();

    for (int t = 0; t < NT - 2; ++t) {
        STAGE(t + 2);
        FRAGS(t);
        VM(4);            // tile t+1 complete for next iter
        BAR();
        LGKM0();
        MM();
        BAR();
    }
    FRAGS(NT - 2);
    VM(0);
    BAR();
    LGKM0();
    MM();
    BAR();
    FRAGS(NT - 1);
    LGKM0();
    MM();

    // Epilogue: e = exp(sim*invT) (diag -> 0); row-sums + positives.
    const float scale = inv_temp(itp) * 1.44269504088896340736f;  // exp2
    float dsum[16];
    #pragma unroll
    for (int i = 0; i < 16; ++i) dsum[i] = 0.f;

    #pragma unroll
    for (int m = 0; m < 4; ++m) {
        #pragma unroll
        for (int n = 0; n < 4; ++n) {
            const int col = colBase + wc * 64 + n * 16 + (l & 15);
            #pragma unroll
            for (int r = 0; r < 4; ++r) {
                const int row = rowBase + wr * 64 + m * 16 + (l >> 4) * 4 + r;
                float e = exp2f(acc[m][n][r] * scale);
                if (col == row) e = 0.f;
                dsum[m * 4 + r] += e;
                const int d = col - row;
                if (d > 0 && (d & (B_ROWS - 1)) == 0) atomicAdd(&pos[row], e);
            }
        }
    }
    #pragma unroll
    for (int i = 0; i < 16; ++i) {
        #pragma unroll
        for (int off = 1; off < 16; off <<= 1)
            dsum[i] += __shfl_xor(dsum[i], off, 64);
    }
    if ((l & 15) == 0) {
        #pragma unroll
        for (int i = 0; i < 16; ++i) {
            const int row = rowBase + wr * 64 + (i >> 2) * 16 + (l >> 4) * 4 + (i & 3);
            atomicAdd(&denom[row], dsum[i]);
        }
    }
#undef BAR
#undef LGKM0
#undef VM

    // Last block computes the loss (all contributions fenced via ticket).
    __shared__ int lastFlag;
    if (tid == 0) {
        __threadfence();
        lastFlag = (atomicAdd(ticket, 1) == (int)gridDim.x - 1) ? 1 : 0;
    }
    __syncthreads();
    if (lastFlag) {
        double s = 0.0;
        for (int i = tid; i < B_ROWS; i += 256) {
            float p = atomicAdd(&pos[i], 0.0f);     // device-coherent read
            float d = atomicAdd(&denom[i], 0.0f);
            s += (double)(-logf(p / (d + 1e-8f)));
        }
        double* buf = (double*)LDS;
        buf[tid] = s;
        __syncthreads();
        for (int off = 128; off >= 1; off >>= 1) {
            if (tid < off) buf[tid] += buf[tid + off];
            __syncthreads();
        }
        if (tid == 0) out[0] = (float)(buf[0] / (double)B_ROWS);
    }
}

extern "C" void kernel_launch(void* const* d_in, const int* in_sizes, int n_in,
                              void* d_out, int out_size, void* d_ws, size_t ws_size,
                              hipStream_t stream) {
    const float* orig   = (const float*)d_in[0];   // [B, D]
    const float* masked = (const float*)d_in[1];   // [M, B, D]
    const int*   itp    = (const int*)d_in[2];     // [1]

    _Float16* E   = (_Float16*)d_ws;                       // [N_COLS][GK] ~20 MB
    float* denom  = (float*)(E + (size_t)N_COLS * GK);     // [B]
    float* pos    = denom + B_ROWS;                        // [B]
    int*   ticket = (int*)(pos + B_ROWS);
    float* out    = (float*)d_out;

    prep_kernel<<<N_COLS / 4 + 1, 256, 0, stream>>>(orig, masked, E, denom, ticket);

    gemm_kernel<<<(B_ROWS / 128) * (N_COLS / 128), 256, 0, stream>>>(E, itp, denom, pos, ticket, out);
}

// Round 14
// 204.639 us; speedup vs baseline: 1.4471x; 1.4471x over previous
//
#include <hip/hip_runtime.h>
#include <math.h>

// ADIOS contrastive loss, MI355X — fp16 MFMA (K=512), 128^2 tile, 4 waves,
// triple-buffered counted-vmcnt pipeline + T2 XOR LDS swizzle.
// R12: REMOVED the ticket/__threadfence loss-fold (suspected cross-XCD L2
// writeback serializer, common to R10/R11 regressions); loss is a separate
// kernel again. Swizzle retained (R11 verified conflicts 1.05e7 -> 0).

#define B_ROWS 4096
#define M_MASK 4
#define D_DIM  512
#define N_COLS ((M_MASK + 1) * B_ROWS)   // 20480
#define GK     D_DIM                     // 512 fp16
#define NT     (GK / 32)                 // 16 K-tiles

typedef _Float16 f16x8 __attribute__((ext_vector_type(8)));
typedef float    f32x4 __attribute__((ext_vector_type(4)));

__device__ __forceinline__ float inv_temp(const int* __restrict__ itp) {
    int it = *itp;
    double T;
    if (it >= 300000) {
        T = 0.05;
    } else {
        double p = (double)it / 300000.0;
        T = 0.05 + 0.5 * (0.2 - 0.05) * (1.0 + cos(3.14159265358979323846 * p));
    }
    return (float)(1.0 / T);
}

// One wave per row: L2-normalize, cast fp16, store [N_COLS][GK].
// Extra block zeroes denom/pos (8192 floats).
__global__ __launch_bounds__(256) void prep_kernel(
        const float* __restrict__ orig, const float* __restrict__ masked,
        _Float16* __restrict__ E, float* __restrict__ zbuf) {
    if (blockIdx.x == N_COLS / 4) {
        float4 z = {0.f, 0.f, 0.f, 0.f};
        #pragma unroll
        for (int i = 0; i < 8; ++i)
            *(float4*)(zbuf + threadIdx.x * 4 + i * 1024) = z;  // 8192 floats
        return;
    }
    int gw = blockIdx.x * 4 + (threadIdx.x >> 6);
    int l  = threadIdx.x & 63;
    const float* row = (gw < B_ROWS) ? orig + (size_t)gw * D_DIM
                                     : masked + (size_t)(gw - B_ROWS) * D_DIM;
    float4 a = *(const float4*)(row + l * 8);
    float4 b = *(const float4*)(row + l * 8 + 4);
    float s = a.x*a.x + a.y*a.y + a.z*a.z + a.w*a.w
            + b.x*b.x + b.y*b.y + b.z*b.z + b.w*b.w;
    #pragma unroll
    for (int off = 1; off < 64; off <<= 1) s += __shfl_xor(s, off, 64);
    float inv = 1.0f / fmaxf(sqrtf(s), 1e-12f);

    f16x8 h;
    h[0] = (_Float16)(a.x*inv); h[1] = (_Float16)(a.y*inv);
    h[2] = (_Float16)(a.z*inv); h[3] = (_Float16)(a.w*inv);
    h[4] = (_Float16)(b.x*inv); h[5] = (_Float16)(b.y*inv);
    h[6] = (_Float16)(b.z*inv); h[7] = (_Float16)(b.w*inv);
    *(f16x8*)(E + (size_t)gw * GK + l * 8) = h;
}

// 128x128 tile, 4 waves (2x2). 3 LDS slots of (A[128][32] | B[128][32]), swizzled.
__global__ __launch_bounds__(256, 3) void gemm_kernel(
        const _Float16* __restrict__ E, const int* __restrict__ itp,
        float* __restrict__ denom, float* __restrict__ pos) {
    __shared__ _Float16 LDS[3 * 8192];   // 48 KiB

    const int tid = threadIdx.x;
    const int l   = tid & 63;
    const int wid = tid >> 6;
    const int wr  = wid >> 1;
    const int wc  = wid & 1;

    const int rowTile = blockIdx.x & 31;     // 4096/128
    const int colTile = blockIdx.x >> 5;     // 20480/128
    const int rowBase = rowTile * 128;
    const int colBase = colTile * 128;

    const _Float16* Ag = E + (size_t)rowBase * GK;
    const _Float16* Bg = E + (size_t)colBase * GK;

    // T2: LDS (r, slot k) holds global k-slot (k ^ ((r>>1)&3)).
    // Staging: lane l writes row r = rc + (l>>2), slot k = l&3; (r>>1)&3 = (l>>3)&3.
    const int ksrc = (((l & 3) ^ ((l >> 3) & 3)) * 8);
    auto STAGE = [&](int t) {
        _Float16* base = LDS + (t % 3) * 8192;
        const int kb = t * 32;
        #pragma unroll
        for (int i = 0; i < 2; ++i) {
            const int rc = wid * 32 + i * 16;
            const int r  = rc + (l >> 2);
            const size_t go = (size_t)r * GK + kb + ksrc;
            __builtin_amdgcn_global_load_lds(
                (const __attribute__((address_space(1))) void*)(Ag + go),
                (__attribute__((address_space(3))) void*)(base + rc * 32), 16, 0, 0);
            __builtin_amdgcn_global_load_lds(
                (const __attribute__((address_space(1))) void*)(Bg + go),
                (__attribute__((address_space(3))) void*)(base + 4096 + rc * 32), 16, 0, 0);
        }
    };

    // Read: lane wants (row = *+ (l&15), slot l>>4) -> LDS slot (l>>4)^((row>>1)&3),
    // and (row>>1)&3 = (l>>1)&3 since the row base is a multiple of 16.
    const int koff = (((l >> 4) ^ ((l >> 1) & 3)) * 8);
    f16x8 af[4], bf[4];
    auto FRAGS = [&](int t) {
        const _Float16* base = LDS + (t % 3) * 8192;
        #pragma unroll
        for (int m = 0; m < 4; ++m)
            af[m] = *(const f16x8*)(base + (wr * 64 + m * 16 + (l & 15)) * 32 + koff);
        #pragma unroll
        for (int n = 0; n < 4; ++n)
            bf[n] = *(const f16x8*)(base + 4096 + (wc * 64 + n * 16 + (l & 15)) * 32 + koff);
    };

    f32x4 acc[4][4];
    #pragma unroll
    for (int m = 0; m < 4; ++m)
        #pragma unroll
        for (int n = 0; n < 4; ++n)
            #pragma unroll
            for (int j = 0; j < 4; ++j) acc[m][n][j] = 0.f;

    auto MM = [&]() {
        __builtin_amdgcn_s_setprio(1);
        #pragma unroll
        for (int m = 0; m < 4; ++m)
            #pragma unroll
            for (int n = 0; n < 4; ++n)
                acc[m][n] = __builtin_amdgcn_mfma_f32_16x16x32_f16(af[m], bf[n], acc[m][n], 0, 0, 0);
        __builtin_amdgcn_s_setprio(0);
    };

#define BAR()  __builtin_amdgcn_s_barrier()
#define LGKM0() { asm volatile("s_waitcnt lgkmcnt(0)" ::: "memory"); \
                  __builtin_amdgcn_sched_barrier(0); }
#define VM(n)  asm volatile("s_waitcnt vmcnt(" #n ")" ::: "memory")

    STAGE(0); STAGE(1);
    VM(4);
    BAR();

    for (int t = 0; t < NT - 2; ++t) {
        STAGE(t + 2);
        FRAGS(t);
        VM(4);            // tile t+1 complete for next iter
        BAR();
        LGKM0();
        MM();
        BAR();
    }
    FRAGS(NT - 2);
    VM(0);
    BAR();
    LGKM0();
    MM();
    BAR();
    FRAGS(NT - 1);
    LGKM0();
    MM();

    // Epilogue: e = exp(sim*invT) (diag -> 0); row-sums + positives.
    const float scale = inv_temp(itp) * 1.44269504088896340736f;  // exp2
    float dsum[16];
    #pragma unroll
    for (int i = 0; i < 16; ++i) dsum[i] = 0.f;

    #pragma unroll
    for (int m = 0; m < 4; ++m) {
        #pragma unroll
        for (int n = 0; n < 4; ++n) {
            const int col = colBase + wc * 64 + n * 16 + (l & 15);
            #pragma unroll
            for (int r = 0; r < 4; ++r) {
                const int row = rowBase + wr * 64 + m * 16 + (l >> 4) * 4 + r;
                float e = exp2f(acc[m][n][r] * scale);
                if (col == row) e = 0.f;
                dsum[m * 4 + r] += e;
                const int d = col - row;
                if (d > 0 && (d & (B_ROWS - 1)) == 0) atomicAdd(&pos[row], e);
            }
        }
    }
    #pragma unroll
    for (int i = 0; i < 16; ++i) {
        #pragma unroll
        for (int off = 1; off < 16; off <<= 1)
            dsum[i] += __shfl_xor(dsum[i], off, 64);
    }
    if ((l & 15) == 0) {
        #pragma unroll
        for (int i = 0; i < 16; ++i) {
            const int row = rowBase + wr * 64 + (i >> 2) * 16 + (l >> 4) * 4 + (i & 3);
            atomicAdd(&denom[row], dsum[i]);
        }
    }
#undef BAR
#undef LGKM0
#undef VM
}

__global__ __launch_bounds__(256) void loss_kernel(
        const float* __restrict__ denom, const float* __restrict__ pos,
        float* __restrict__ out) {
    __shared__ double buf[256];
    double s = 0.0;
    for (int i = threadIdx.x; i < B_ROWS; i += 256) {
        float p = pos[i];
        float d = denom[i] + 1e-8f;
        s += (double)(-logf(p / d));
    }
    buf[threadIdx.x] = s;
    __syncthreads();
    for (int off = 128; off >= 1; off >>= 1) {
        if (threadIdx.x < off) buf[threadIdx.x] += buf[threadIdx.x + off];
        __syncthreads();
    }
    if (threadIdx.x == 0) out[0] = (float)(buf[0] / (double)B_ROWS);
}

extern "C" void kernel_launch(void* const* d_in, const int* in_sizes, int n_in,
                              void* d_out, int out_size, void* d_ws, size_t ws_size,
                              hipStream_t stream) {
    const float* orig   = (const float*)d_in[0];   // [B, D]
    const float* masked = (const float*)d_in[1];   // [M, B, D]
    const int*   itp    = (const int*)d_in[2];     // [1]

    _Float16* E   = (_Float16*)d_ws;                       // [N_COLS][GK] ~20 MB
    float* denom  = (float*)(E + (size_t)N_COLS * GK);     // [B]
    float* pos    = denom + B_ROWS;                        // [B]
    float* out    = (float*)d_out;

    prep_kernel<<<N_COLS / 4 + 1, 256, 0, stream>>>(orig, masked, E, denom);

    gemm_kernel<<<(B_ROWS / 128) * (N_COLS / 128), 256, 0, stream>>>(E, itp, denom, pos);

    loss_kernel<<<1, 256, 0, stream>>>(denom, pos, out);
}